// Round 1
// baseline (252.894 us; speedup 1.0000x reference)
//
#include <hip/hip_runtime.h>
#include <hip/hip_bf16.h>

using bf16 = __hip_bfloat16;
typedef __attribute__((ext_vector_type(8))) short short8;     // 8 bf16 MFMA a/b frag
typedef __attribute__((ext_vector_type(4))) float floatx4;    // 16x16 MFMA c/d frag
typedef __attribute__((ext_vector_type(16))) float floatx16;  // 32x32 MFMA c/d frag

#define NEG_INF (-__builtin_huge_valf())

// async global->LDS, 16B per lane. LDS dest is wave-uniform base + lane*16.
__device__ __forceinline__ void gld_lds16(const void* g, void* l) {
  __builtin_amdgcn_global_load_lds(
      (const __attribute__((address_space(1))) unsigned int*)g,
      (__attribute__((address_space(3))) unsigned int*)l, 16, 0, 0);
}

template <int N> __device__ __forceinline__ void wait_vm() {
  asm volatile("s_waitcnt vmcnt(%0)" ::"n"(N) : "memory");
}
__device__ __forceinline__ void bar() {
  asm volatile("" ::: "memory");
  __builtin_amdgcn_s_barrier();
  asm volatile("" ::: "memory");
}

__device__ __forceinline__ void cvt8(const float4& a, const float4& b, bf16* t) {
  t[0] = __float2bfloat16(a.x); t[1] = __float2bfloat16(a.y);
  t[2] = __float2bfloat16(a.z); t[3] = __float2bfloat16(a.w);
  t[4] = __float2bfloat16(b.x); t[5] = __float2bfloat16(b.y);
  t[6] = __float2bfloat16(b.z); t[7] = __float2bfloat16(b.w);
}

// ---------------- inputs fp32 -> bf16 (query ++ keys ++ qw ++ kw) ----------
// totals: 4194304 + 8388608 + 262144 + 262144 = 13107200 elems = 6400*256*8
__global__ __launch_bounds__(256) void cvt_in(const float* __restrict__ q,
                                              const float* __restrict__ k,
                                              const float* __restrict__ qw,
                                              const float* __restrict__ kw,
                                              bf16* __restrict__ qo, bf16* __restrict__ ko,
                                              bf16* __restrict__ qwo, bf16* __restrict__ kwo) {
  const size_t e = ((size_t)blockIdx.x * 256 + threadIdx.x) * 8;
  const float* src; bf16* dst;
  if (e < 4194304)       { src = q  + e;              dst = qo  + e; }
  else if (e < 12582912) { src = k  + (e - 4194304);  dst = ko  + (e - 4194304); }
  else if (e < 12845056) { src = qw + (e - 12582912); dst = qwo + (e - 12582912); }
  else                   { src = kw + (e - 12845056); dst = kwo + (e - 12845056); }
  float4 a = *(const float4*)src;
  float4 c = *(const float4*)(src + 4);
  bf16 t[8];
  cvt8(a, c, t);
  *(short8*)dst = *(short8*)t;
}

// 32x32x16 MFMA block: wave covers 64x64 as 2x2 of 32x32 tiles.
// A/B operand: m|n = lane&31, k = (lane>>5)*8 + j  (row-major [rows][32] LDS tile)
// C/D: col = lane&31, row = (reg&3) + 8*(reg>>2) + 4*(lane>>5)   [m74/m101]
__device__ __forceinline__ void mfma_tile32(const bf16* sAh, const bf16* sBh,
                                            int wm, int wn, int lane,
                                            floatx16 acc[2][2]) {
  const int fm = lane & 31;
  const int fk = (lane >> 5) * 8;
  #pragma unroll
  for (int ks = 0; ks < 2; ++ks) {
    short8 a0 = *(const short8*)(sAh + (wm +  0 + fm) * 32 + ks * 16 + fk);
    short8 a1 = *(const short8*)(sAh + (wm + 32 + fm) * 32 + ks * 16 + fk);
    short8 b0 = *(const short8*)(sBh + (wn +  0 + fm) * 32 + ks * 16 + fk);
    short8 b1 = *(const short8*)(sBh + (wn + 32 + fm) * 32 + ks * 16 + fk);
    acc[0][0] = __builtin_amdgcn_mfma_f32_32x32x16_bf16(a0, b0, acc[0][0], 0, 0, 0);
    acc[0][1] = __builtin_amdgcn_mfma_f32_32x32x16_bf16(a0, b1, acc[0][1], 0, 0, 0);
    acc[1][0] = __builtin_amdgcn_mfma_f32_32x32x16_bf16(a1, b0, acc[1][0], 0, 0, 0);
    acc[1][1] = __builtin_amdgcn_mfma_f32_32x32x16_bf16(a1, b1, acc[1][1], 0, 0, 0);
  }
}

// ---------------- projection: out_bf16 = A_bf16 . W_bf16^T + b --------------
// blockIdx.x in [0,64) -> Q rows (8192), [64,192) -> K rows (16384).
__global__ __launch_bounds__(256) void proj(const bf16* __restrict__ Xq,
                                            const bf16* __restrict__ Xk,
                                            const bf16* __restrict__ qw,
                                            const bf16* __restrict__ kw,
                                            const float* __restrict__ qb,
                                            const float* __restrict__ kb,
                                            bf16* __restrict__ qo,
                                            bf16* __restrict__ ko) {
  __shared__ bf16 sA[2][128 * 32];
  __shared__ bf16 sB[2][128 * 32];
  const int mt = blockIdx.x;
  const bool isQ = mt < 64;
  const bf16* A    = isQ ? Xq : Xk;
  const bf16* W    = isQ ? qw : kw;
  const float* bias = isQ ? qb : kb;
  bf16* outp       = isQ ? qo : ko;
  const int m0 = (isQ ? mt : mt - 64) * 128;
  const int n0 = blockIdx.y * 128;

  const int tid  = threadIdx.x;
  const int lane = tid & 63;
  const int w    = tid >> 6;
  const int wm   = (w >> 1) * 64;
  const int wn   = (w & 1) * 64;
  const int st_row = lane >> 2;
  const int st_col = (lane & 3) * 8;

  floatx16 acc[2][2];
  #pragma unroll
  for (int mi = 0; mi < 2; ++mi)
    #pragma unroll
    for (int ni = 0; ni < 2; ++ni)
      #pragma unroll
      for (int r = 0; r < 16; ++r)
        acc[mi][ni][r] = 0.f;

  for (int kt = 0; kt < 512; kt += 64) {
    #pragma unroll
    for (int h = 0; h < 2; ++h)
      #pragma unroll
      for (int j = 0; j < 2; ++j) {
        const int r = (w << 5) + (j << 4);
        gld_lds16(A + (size_t)(m0 + r + st_row) * 512 + kt + h * 32 + st_col,
                  &sA[h][r * 32]);
        gld_lds16(W + (size_t)(n0 + r + st_row) * 512 + kt + h * 32 + st_col,
                  &sB[h][r * 32]);
      }
    __syncthreads();
    #pragma unroll
    for (int h = 0; h < 2; ++h)
      mfma_tile32(sA[h], sB[h], wm, wn, lane, acc);
    __syncthreads();
  }

  const int col = lane & 31;
  const int rhi = (lane >> 5) * 4;
  #pragma unroll
  for (int ni = 0; ni < 2; ++ni) {
    const int gn = n0 + wn + ni * 32 + col;
    const float bv = bias[gn];
    #pragma unroll
    for (int mi = 0; mi < 2; ++mi)
      #pragma unroll
      for (int reg = 0; reg < 16; ++reg) {
        const int row = (reg & 3) + 8 * (reg >> 2) + rhi;
        outp[(size_t)(m0 + wm + mi * 32 + row) * 512 + gn] =
            __float2bfloat16(acc[mi][ni][reg] + bv);
      }
  }
}

// ---------------- QK^T: 256x256 tile, BK=64, 8 waves, counted-vmcnt pipeline
// LDS halves per K-tile: [0]=A rows 0-127, [1]=A rows 128-255,
//                        [2]=B rows 0-127, [3]=B rows 128-255 (each 16 KiB).
// Within a half: 16x32-bf16 subtiles (1024 B), storage byte for logical (r,c):
//   off = ((r>>4)*2 + (cbyte>>6))*1024 + (r&15)*64 + ((cbyte&63) ^ swz(r)),
//   swz(r) = ((r&8)<<2) ^ ((r&2)<<3)   -> conflict-free ds_read_b128 (uniform
//   8 accesses/bank over the wave; verified by enumeration).
// global_load_lds writes LDS linearly; the global SOURCE address carries the
// inverse swizzle (rule: linear dest + inv-swz source + swz on read).
__global__ __launch_bounds__(512, 2) void qk8(const bf16* __restrict__ Q,
                                              const bf16* __restrict__ Kp,
                                              const unsigned char* __restrict__ mask,
                                              float* __restrict__ out) {
  __shared__ alignas(16) char smem[2][4][16384];   // 128 KiB

  const int bid = blockIdx.x;
  const int sb  = ((bid & 7) << 6) | (bid >> 3);   // bijective XCD swizzle (512%8==0)
  const int b   = sb >> 7;
  const int mt  = (sb >> 4) & 7;
  const int nt  = sb & 15;

  const bf16* Qb = Q  + ((size_t)b * 2048 + (size_t)mt * 256) * 512;
  const bf16* Kb = Kp + ((size_t)b * 4096 + (size_t)nt * 256) * 512;

  const int tid  = threadIdx.x;
  const int lane = tid & 63;
  const int w    = tid >> 6;       // wave 0..7
  const int wm   = w >> 2;         // 0..1  (M half: 128 rows)
  const int wn   = w & 3;          // 0..3  (N quarter: 64 cols)
  const int l15  = lane & 15;
  const int kg   = lane >> 4;      // 0..3
  // per-thread fragment byte offset inside a half (swizzled)
  const int aoff = l15 * 64 + ((kg << 4) ^ ((l15 & 8) << 2) ^ ((l15 & 2) << 3));

  auto stage = [&](int t) {        // stage K-tile t into dbuf t&1 (8 loads/thread)
    const int kt = t * 64;
    char* dst = &smem[t & 1][0][0];
    #pragma unroll
    for (int hf = 0; hf < 4; ++hf) {
      const bf16* src = (hf < 2) ? Qb : Kb;
      const int rb = (hf & 1) * 128;
      #pragma unroll
      for (int L = 0; L < 2; ++L) {
        const int lin = tid * 16 + L * 8192;          // linear byte in half
        const int sub = lin >> 10;
        const int r   = ((sub >> 1) << 4) | ((lin >> 6) & 15);
        const int swz = ((r & 8) << 2) ^ ((r & 2) << 3);
        const int cby = ((sub & 1) << 6) | ((lin & 63) ^ swz);
        gld_lds16(src + (size_t)(rb + r) * 512 + kt + (cby >> 1),
                  dst + hf * 16384 + L * 8192 + w * 1024);
      }
    }
  };

  floatx4 acc[8][4];
  #pragma unroll
  for (int i = 0; i < 8; ++i)
    #pragma unroll
    for (int j = 0; j < 4; ++j)
      acc[i][j] = (floatx4){0.f, 0.f, 0.f, 0.f};

  stage(0);
  stage(1);
  wait_vm<8>();                    // tile 0 landed (own share); tile 1 in flight
  bar();

  #pragma unroll
  for (int t = 0; t < 8; ++t) {
    const char* Ah = &smem[t & 1][wm][0];
    const char* Bh = &smem[t & 1][2 + (wn >> 1)][0];
    const int bfb = (wn & 1) * 4;  // B frag-row base within half
    #pragma unroll
    for (int rh = 0; rh < 2; ++rh) {
      short8 a[4][2];
      #pragma unroll
      for (int fr = 0; fr < 4; ++fr)
        #pragma unroll
        for (int ks = 0; ks < 2; ++ks)
          a[fr][ks] = *(const short8*)(Ah + (rh * 4 + fr) * 2048 + ks * 1024 + aoff);
      #pragma unroll
      for (int ch = 0; ch < 2; ++ch) {
        short8 bb[2][2];
        #pragma unroll
        for (int fn = 0; fn < 2; ++fn)
          #pragma unroll
          for (int ks = 0; ks < 2; ++ks)
            bb[fn][ks] = *(const short8*)(Bh + (bfb + ch * 2 + fn) * 2048 + ks * 1024 + aoff);
        __builtin_amdgcn_s_setprio(1);
        #pragma unroll
        for (int fr = 0; fr < 4; ++fr)
          #pragma unroll
          for (int fn = 0; fn < 2; ++fn)
            #pragma unroll
            for (int ks = 0; ks < 2; ++ks)
              acc[rh * 4 + fr][ch * 2 + fn] = __builtin_amdgcn_mfma_f32_16x16x32_bf16(
                  a[fr][ks], bb[fn][ks], acc[rh * 4 + fr][ch * 2 + fn], 0, 0, 0);
        __builtin_amdgcn_s_setprio(0);
      }
    }
    if (t < 7) {
      bar();                       // all waves done reading dbuf t&1
      if (t < 6) { stage(t + 2); wait_vm<8>(); }  // keep next tile's 8 in flight
      else       { wait_vm<0>(); }                // last prefetch: full drain
      bar();                       // cross-wave: tile t+1 fully resident
    }
  }

  // epilogue: scale 1/(N_HEADS*sqrt(HEAD_DIM)) = 1/64, mask -> -inf
  float* ob = out + (size_t)b * 2048 * 4096
                  + ((size_t)mt * 256 + (size_t)wm * 128) * 4096
                  + (size_t)nt * 256 + wn * 64;
  const unsigned char* mb = mask + (size_t)b * 4096 + nt * 256 + wn * 64;
  #pragma unroll
  for (int fc = 0; fc < 4; ++fc) {
    const int c = fc * 16 + l15;
    const bool msk = mb[c] != 0;
    #pragma unroll
    for (int f8 = 0; f8 < 8; ++f8)
      #pragma unroll
      for (int r = 0; r < 4; ++r)
        ob[(size_t)(f8 * 16 + kg * 4 + r) * 4096 + c] =
            msk ? NEG_INF : acc[f8][fc][r] * (1.f / 64.f);
  }
}

extern "C" void kernel_launch(void* const* d_in, const int* in_sizes, int n_in,
                              void* d_out, int out_size, void* d_ws, size_t ws_size,
                              hipStream_t stream) {
  const float* query = (const float*)d_in[0];
  const float* keys  = (const float*)d_in[1];
  const unsigned char* mask = (const unsigned char*)d_in[2];  // numpy bool = 1B
  const float* q_w = (const float*)d_in[3];
  const float* q_b = (const float*)d_in[4];
  const float* k_w = (const float*)d_in[5];
  const float* k_b = (const float*)d_in[6];
  float* out = (float*)d_out;

  const size_t nq = 4194304;   // 8192*512
  const size_t nk = 8388608;   // 16384*512
  const size_t nw = 262144;    // 512*512

  // workspace carve (bf16), ~49 MiB total
  char* ws = (char*)d_ws;
  bf16* q_bf   = (bf16*)ws;
  bf16* k_bf   = (bf16*)(ws + nq * 2);
  bf16* qw_bf  = (bf16*)(ws + (nq + nk) * 2);
  bf16* kw_bf  = (bf16*)(ws + (nq + nk + nw) * 2);
  bf16* q_proj = (bf16*)(ws + (nq + nk + 2 * nw) * 2);
  bf16* k_proj = (bf16*)(ws + (2 * nq + nk + 2 * nw) * 2);

  cvt_in<<<6400, 256, 0, stream>>>(query, keys, q_w, k_w, q_bf, k_bf, qw_bf, kw_bf);
  proj<<<dim3(192, 4), 256, 0, stream>>>(q_bf, k_bf, qw_bf, kw_bf, q_b, k_b,
                                         q_proj, k_proj);
  qk8<<<512, 512, 0, stream>>>(q_proj, k_proj, mask, out);
}